// Round 12
// baseline (314.011 us; speedup 1.0000x reference)
//
#include <hip/hip_runtime.h>

#define Bn 8
#define Vn 3
#define Hn 512
#define Wn 640
#define Nn (Hn * Wn)
#define PX 8                      // pixels per thread in compact
#define TPB 256
#define XBLKS (Nn / (TPB * PX))   // 160 blocks per (b,i)
#define GRID1 (XBLKS * Vn * Bn)   // 3840
#define CAPL 131072               // records per (b,i) list (expect ~85-100k)
#define NCH 128                   // chunks per list in pairs
#define GRID2 (Bn * Vn * NCH)     // 3072

struct __attribute__((aligned(4))) fpair { float a, b; };

__device__ __forceinline__ float rfl(float x) {
    return __int_as_float(__builtin_amdgcn_readfirstlane(__float_as_int(x)));
}

// Inline P = K * RT_j * inv(RT_i) * inv(K), rows 0..2, analytic affine inverses.
// MUST be identical in both kernels so compact's predicate == pairs' inb bitwise.
// (Validated R10/R11: absmax 0.0 vs reference's numerical inverses.)
__device__ __forceinline__ void computeQ(const float* __restrict__ K,
                                         const float* __restrict__ RT,
                                         int b, int i, float Q[Vn][12]) {
    const float* Kb = K + (size_t)b * 16;
    const float f  = Kb[0], cx = Kb[2], cy = Kb[6];
    const float rf = 1.0f / f;
    const float* Ti = RT + (size_t)(b * Vn + i) * 16;
    const float A00=Ti[0], A01=Ti[1], A02=Ti[2],  A03=Ti[3];
    const float A10=Ti[4], A11=Ti[5], A12=Ti[6],  A13=Ti[7];
    const float A20=Ti[8], A21=Ti[9], A22=Ti[10], A23=Ti[11];
    const float I00=A00, I01=A10, I02=A20, I03=-(A00*A03 + A10*A13 + A20*A23);
    const float I10=A01, I11=A11, I12=A21, I13=-(A01*A03 + A11*A13 + A21*A23);
    const float I20=A02, I21=A12, I22=A22, I23=-(A02*A03 + A12*A13 + A22*A23);
    #pragma unroll
    for (int j = 0; j < Vn; ++j) {
        const float* Tj = RT + (size_t)(b * Vn + j) * 16;
        const float B00=Tj[0], B01=Tj[1], B02=Tj[2],  B03=Tj[3];
        const float B10=Tj[4], B11=Tj[5], B12=Tj[6],  B13=Tj[7];
        const float B20=Tj[8], B21=Tj[9], B22=Tj[10], B23=Tj[11];
        const float M00=B00*I00+B01*I10+B02*I20, M01=B00*I01+B01*I11+B02*I21,
                    M02=B00*I02+B01*I12+B02*I22, M03=B00*I03+B01*I13+B02*I23+B03;
        const float M10=B10*I00+B11*I10+B12*I20, M11=B10*I01+B11*I11+B12*I21,
                    M12=B10*I02+B11*I12+B12*I22, M13=B10*I03+B11*I13+B12*I23+B13;
        const float M20=B20*I00+B21*I10+B22*I20, M21=B20*I01+B21*I11+B22*I21,
                    M22=B20*I02+B21*I12+B22*I22, M23=B20*I03+B21*I13+B22*I23+B23;
        const float G00=f*M00+cx*M20, G01=f*M01+cx*M21, G02=f*M02+cx*M22, G03=f*M03+cx*M23;
        const float G10=f*M10+cy*M20, G11=f*M11+cy*M21, G12=f*M12+cy*M22, G13=f*M13+cy*M23;
        const float G20=M20,          G21=M21,          G22=M22,          G23=M23;
        Q[j][0]  = rfl(G00*rf);  Q[j][1]  = rfl(G01*rf);
        Q[j][2]  = rfl(G02 - (cx*rf)*G00 - (cy*rf)*G01);  Q[j][3]  = rfl(G03);
        Q[j][4]  = rfl(G10*rf);  Q[j][5]  = rfl(G11*rf);
        Q[j][6]  = rfl(G12 - (cx*rf)*G10 - (cy*rf)*G11);  Q[j][7]  = rfl(G13);
        Q[j][8]  = rfl(G20*rf);  Q[j][9]  = rfl(G21*rf);
        Q[j][10] = rfl(G22 - (cx*rf)*G20 - (cy*rf)*G21);  Q[j][11] = rfl(G23);
    }
}

// ---------- Stage 1: predicate + WAVE-DIRECT compaction -> per-(b,i) lists ----
// Per wave: 8 ballots, ONE global atomic for the wave's total, then lanes write
// records at consecutive slots (coalesced by construction). No LDS, no barriers.
__global__ __launch_bounds__(TPB) void compact_kernel(const float* __restrict__ pred,
                                                      const float* __restrict__ K,
                                                      const float* __restrict__ RT,
                                                      unsigned* __restrict__ list_cnt,
                                                      uint2* __restrict__ lists) {
    const int id   = blockIdx.x;
    const int b    = id & 7;
    const int r    = id >> 3;
    const int i    = r % Vn;
    const int xblk = r / Vn;
    const int L    = b * Vn + i;

    float Q[Vn][12];
    computeQ(K, RT, b, i, Q);

    const int base = (xblk * TPB + threadIdx.x) * PX;
    const int yrow = base / Wn;
    const int xcol = base - yrow * Wn;
    const float fy = (float)yrow;

    const float* dptr = pred + (size_t)L * Nn + base;
    float dv[PX];
    {
        const float4 a0 = *reinterpret_cast<const float4*>(dptr);
        const float4 a1 = *reinterpret_cast<const float4*>(dptr + 4);
        dv[0] = a0.x; dv[1] = a0.y; dv[2] = a0.z; dv[3] = a0.w;
        dv[4] = a1.x; dv[5] = a1.y; dv[6] = a1.z; dv[7] = a1.w;
    }

    // per-row constants (fy uniform per thread)
    float RXc[Vn], RYc[Vn];
    #pragma unroll
    for (int j = 0; j < Vn; ++j) {
        RXc[j] = fmaf(Q[j][1], fy, Q[j][2]);
        RYc[j] = fmaf(Q[j][5], fy, Q[j][6]);
    }

    const int lane = threadIdx.x & 63;
    bool act[PX];
    unsigned long long mk[PX];
    unsigned total = 0;
    #pragma unroll
    for (int k = 0; k < PX; ++k) {
        const float d  = dv[k];
        const float fx = (float)(xcol + k);
        bool a = false;
        #pragma unroll
        for (int j = 0; j < Vn; ++j) {
            const float X = fmaf(d, fmaf(Q[j][0], fx, RXc[j]), Q[j][3]);
            const float Y = fmaf(d, fmaf(Q[j][4], fx, RYc[j]), Q[j][7]);
            a |= (X >= 0.0f) & (X <= (float)(Wn - 1)) &
                 (Y >= 0.0f) & (Y <= (float)(Hn - 1));
        }
        act[k] = a;
        mk[k]  = __ballot(a);
        total += (unsigned)__popcll(mk[k]);
    }

    unsigned wbase = 0;
    if (lane == 0 && total) wbase = atomicAdd(&list_cnt[L], total);
    wbase = (unsigned)__shfl((int)wbase, 0, 64);

    uint2* dst = lists + (size_t)L * CAPL;
    unsigned off = wbase;
    #pragma unroll
    for (int k = 0; k < PX; ++k) {
        if (act[k]) {
            const unsigned slot = off + (unsigned)__popcll(mk[k] & ((1ULL << lane) - 1ULL));
            if (slot < CAPL)
                dst[slot] = make_uint2((unsigned)(xcol + k) | ((unsigned)yrow << 16),
                                       __float_as_uint(dv[k]));
        }
        off += (unsigned)__popcll(mk[k]);
    }
}

// ---------- Stage 2: dense dual-record processing; fused finalize ----------
__global__ __launch_bounds__(TPB) void pairs_kernel(const float* __restrict__ pred,
                                                    const float* __restrict__ K,
                                                    const float* __restrict__ RT,
                                                    const unsigned* __restrict__ list_cnt,
                                                    const uint2* __restrict__ lists,
                                                    float* __restrict__ accum,
                                                    unsigned* __restrict__ counter,
                                                    float* __restrict__ out) {
    const int id    = blockIdx.x;
    const int b     = id & 7;          // XCD-batch locality, same mapping as compact
    const int r     = id >> 3;
    const int i     = r % Vn;
    const int chunk = r / Vn;
    const int L     = b * Vn + i;

    float Q[Vn][12];
    computeQ(K, RT, b, i, Q);

    unsigned count = list_cnt[L];
    if (count > CAPL) count = CAPL;
    const uint2* __restrict__ myl = lists + (size_t)L * CAPL;

    const float cW = (float)Wn / (float)(Wn - 1);
    const float cH = (float)Hn / (float)(Hn - 1);
    const unsigned step = NCH * TPB;

    float num[Vn] = {0.0f, 0.0f, 0.0f};
    float den[Vn] = {0.0f, 0.0f, 0.0f};

    for (unsigned t = (unsigned)chunk * TPB + threadIdx.x; t < count; t += 2u * step) {
        const unsigned t1 = t + step;
        const bool v1 = (t1 < count);
        const uint2 rec0 = myl[t];
        const uint2 rec1 = v1 ? myl[t1] : rec0;

        float fxq[2], fyq[2], dq[2];
        fxq[0] = (float)(rec0.x & 0xffffu); fyq[0] = (float)(rec0.x >> 16);
        dq[0]  = __uint_as_float(rec0.y);
        fxq[1] = (float)(rec1.x & 0xffffu); fyq[1] = (float)(rec1.x >> 16);
        dq[1]  = __uint_as_float(rec1.y);
        const bool vq[2] = {true, v1};

        // phase A: projections, addresses, weights for both records x 3 pairs
        int   ad0[2][Vn], ad1[2][Vn];
        float w00[2][Vn], w10[2][Vn], wy0v[2][Vn], wy1v[2][Vn], Zs[2][Vn], ms[2][Vn];
        bool  xloA[2][Vn], xhiA[2][Vn];
        #pragma unroll
        for (int q = 0; q < 2; ++q) {
            const float d = dq[q], fx = fxq[q], fyr = fyq[q];
            #pragma unroll
            for (int j = 0; j < Vn; ++j) {
                const float RXd = fmaf(Q[j][1], fyr, Q[j][2]);
                const float RYd = fmaf(Q[j][5], fyr, Q[j][6]);
                const float RZd = fmaf(Q[j][9], fyr, Q[j][10]);
                const float X = fmaf(d, fmaf(Q[j][0], fx, RXd), Q[j][3]);
                const float Y = fmaf(d, fmaf(Q[j][4], fx, RYd), Q[j][7]);
                const float Z = fmaf(d, fmaf(Q[j][8], fx, RZd), Q[j][11]);
                const bool inb = vq[q] & (X >= 0.0f) & (X <= (float)(Wn - 1)) &
                                         (Y >= 0.0f) & (Y <= (float)(Hn - 1));
                const float ix = fmaf(X, cW, -0.5f);
                const float iy = fmaf(Y, cH, -0.5f);
                const float x0f = floorf(ix);
                const float y0f = floorf(iy);
                const float wx1 = ix - x0f;
                const float wy1 = iy - y0f;
                const float wx0 = 1.0f - wx1;
                const float wy0 = 1.0f - wy1;
                const int x0 = (int)x0f;
                const int y0 = (int)y0f;
                const int x1 = x0 + 1;
                const int y1 = y0 + 1;
                const int cx2 = min(max(x0, 0), Wn - 2);
                const int cy0 = min(max(y0, 0), Hn - 1);
                const int cy1 = min(max(y1, 0), Hn - 1);
                ad0[q][j] = cy0 * Wn + cx2;
                ad1[q][j] = cy1 * Wn + cx2;
                xloA[q][j] = (x0 >= 0);
                xhiA[q][j] = (x0 <= Wn - 2);
                w00[q][j]  = (inb && xloA[q][j])   ? wx0 : 0.0f;
                w10[q][j]  = (inb && (x1 < Wn))    ? wx1 : 0.0f;
                wy0v[q][j] = (inb && (y0 >= 0))    ? wy0 : 0.0f;
                wy1v[q][j] = (inb && (y1 < Hn))    ? wy1 : 0.0f;
                Zs[q][j]   = inb ? Z : 0.0f;
                ms[q][j]   = inb ? 1.0f : 0.0f;
            }
        }
        // phase B: 12 paired gathers back-to-back
        fpair q0[2][Vn], q1[2][Vn];
        #pragma unroll
        for (int q = 0; q < 2; ++q)
            #pragma unroll
            for (int j = 0; j < Vn; ++j) {
                const float* img = pred + (size_t)(b * Vn + j) * Nn;
                q0[q][j] = *reinterpret_cast<const fpair*>(img + ad0[q][j]);
                q1[q][j] = *reinterpret_cast<const fpair*>(img + ad1[q][j]);
            }
        // phase C: consume
        #pragma unroll
        for (int q = 0; q < 2; ++q)
            #pragma unroll
            for (int j = 0; j < Vn; ++j) {
                const float c00 = xhiA[q][j] ? q0[q][j].a : q0[q][j].b;
                const float c10 = xloA[q][j] ? q0[q][j].b : q0[q][j].a;
                const float c01 = xhiA[q][j] ? q1[q][j].a : q1[q][j].b;
                const float c11 = xloA[q][j] ? q1[q][j].b : q1[q][j].a;
                const float top = fmaf(w00[q][j], c00, w10[q][j] * c10);
                const float bot = fmaf(w00[q][j], c01, w10[q][j] * c11);
                const float warped = fmaf(wy0v[q][j], top, wy1v[q][j] * bot);
                num[j] += fabsf(warped - Zs[q][j]);
                den[j] += ms[q][j];
            }
    }

    // reduction: wave-64 shuffle over 6 accumulators
    #pragma unroll
    for (int off = 32; off > 0; off >>= 1) {
        #pragma unroll
        for (int j = 0; j < Vn; ++j) {
            num[j] += __shfl_down(num[j], off, 64);
            den[j] += __shfl_down(den[j], off, 64);
        }
    }
    __shared__ float s_red[4][2 * Vn];
    __shared__ int s_last;
    const int lane = threadIdx.x & 63;
    const int wid  = threadIdx.x >> 6;
    if (lane == 0) {
        #pragma unroll
        for (int j = 0; j < Vn; ++j) {
            s_red[wid][2 * j + 0] = num[j];
            s_red[wid][2 * j + 1] = den[j];
        }
    }
    __syncthreads();
    if (threadIdx.x < 2 * Vn) {
        const int slot = threadIdx.x;
        const float v = s_red[0][slot] + s_red[1][slot] + s_red[2][slot] + s_red[3][slot];
        const int j = slot >> 1;
        const int comp = slot & 1;
        atomicAdd(&accum[(i * Vn + j) * 2 + comp], v);
    }
    __syncthreads();
    if (threadIdx.x == 0) {
        __threadfence();
        const unsigned old = atomicAdd(counter, 1u);
        s_last = (old == (unsigned)(GRID2 - 1)) ? 1 : 0;
    }
    __syncthreads();
    if (s_last && threadIdx.x == 0) {
        float tt = 0.0f;
        for (int pr = 0; pr < Vn * Vn; ++pr) {
            const float nn = atomicAdd(&accum[pr * 2 + 0], 0.0f);
            const float dd = atomicAdd(&accum[pr * 2 + 1], 0.0f);
            tt += nn / fmaxf(dd, 1.0f);
        }
        out[0] = tt;
    }
}

extern "C" void kernel_launch(void* const* d_in, const int* in_sizes, int n_in,
                              void* d_out, int out_size, void* d_ws, size_t ws_size,
                              hipStream_t stream) {
    const float* pred = (const float*)d_in[0];   // (B,V,H,W)
    const float* K    = (const float*)d_in[1];   // (B,4,4)
    const float* RT   = (const float*)d_in[2];   // (B,V,4,4)
    float* out = (float*)d_out;

    float*    accum    = (float*)d_ws;                    // 24 floats
    unsigned* counter  = (unsigned*)d_ws + 24;            // ticket
    unsigned* list_cnt = (unsigned*)d_ws + 32;            // 24 counters
    uint2*    lists    = (uint2*)((char*)d_ws + 1024);    // 24*CAPL*8B = 25 MB

    hipMemsetAsync(d_ws, 0, 512, stream);
    compact_kernel<<<GRID1, TPB, 0, stream>>>(pred, K, RT, list_cnt, lists);
    pairs_kernel<<<GRID2, TPB, 0, stream>>>(pred, K, RT, list_cnt, lists,
                                            accum, counter, out);
}

// Round 13
// 179.663 us; speedup vs baseline: 1.7478x; 1.7478x over previous
//
#include <hip/hip_runtime.h>

#define Bn 8
#define Vn 3
#define Hn 512
#define Wn 640
#define Nn (Hn * Wn)
#define PX 8                      // pixels per thread in compact
#define TPB 256
#define XBLKS (Nn / (TPB * PX))   // 160 blocks per (b,i)
#define GRID1 (XBLKS * Vn * Bn)   // 3840
#define CAPL 131072               // records per (b,i) list (expect ~85-100k)
#define NCH 64                    // chunks per list -> GRID2 = 1536 = 6/CU, fully resident
#define GRID2 (Bn * Vn * NCH)

struct __attribute__((aligned(4))) fpair { float a, b; };

__device__ __forceinline__ float rfl(float x) {
    return __int_as_float(__builtin_amdgcn_readfirstlane(__float_as_int(x)));
}

// Inline P = K * RT_j * inv(RT_i) * inv(K), rows 0..2, analytic affine inverses.
// Identical in both kernels -> compact's predicate == pairs' inb bitwise.
// (Validated R10/R11: absmax 0.0 vs reference.)
__device__ __forceinline__ void computeQ(const float* __restrict__ K,
                                         const float* __restrict__ RT,
                                         int b, int i, float Q[Vn][12]) {
    const float* Kb = K + (size_t)b * 16;
    const float f  = Kb[0], cx = Kb[2], cy = Kb[6];
    const float rf = 1.0f / f;
    const float* Ti = RT + (size_t)(b * Vn + i) * 16;
    const float A00=Ti[0], A01=Ti[1], A02=Ti[2],  A03=Ti[3];
    const float A10=Ti[4], A11=Ti[5], A12=Ti[6],  A13=Ti[7];
    const float A20=Ti[8], A21=Ti[9], A22=Ti[10], A23=Ti[11];
    const float I00=A00, I01=A10, I02=A20, I03=-(A00*A03 + A10*A13 + A20*A23);
    const float I10=A01, I11=A11, I12=A21, I13=-(A01*A03 + A11*A13 + A21*A23);
    const float I20=A02, I21=A12, I22=A22, I23=-(A02*A03 + A12*A13 + A22*A23);
    #pragma unroll
    for (int j = 0; j < Vn; ++j) {
        const float* Tj = RT + (size_t)(b * Vn + j) * 16;
        const float B00=Tj[0], B01=Tj[1], B02=Tj[2],  B03=Tj[3];
        const float B10=Tj[4], B11=Tj[5], B12=Tj[6],  B13=Tj[7];
        const float B20=Tj[8], B21=Tj[9], B22=Tj[10], B23=Tj[11];
        const float M00=B00*I00+B01*I10+B02*I20, M01=B00*I01+B01*I11+B02*I21,
                    M02=B00*I02+B01*I12+B02*I22, M03=B00*I03+B01*I13+B02*I23+B03;
        const float M10=B10*I00+B11*I10+B12*I20, M11=B10*I01+B11*I11+B12*I21,
                    M12=B10*I02+B11*I12+B12*I22, M13=B10*I03+B11*I13+B12*I23+B13;
        const float M20=B20*I00+B21*I10+B22*I20, M21=B20*I01+B21*I11+B22*I21,
                    M22=B20*I02+B21*I12+B22*I22, M23=B20*I03+B21*I13+B22*I23+B23;
        const float G00=f*M00+cx*M20, G01=f*M01+cx*M21, G02=f*M02+cx*M22, G03=f*M03+cx*M23;
        const float G10=f*M10+cy*M20, G11=f*M11+cy*M21, G12=f*M12+cy*M22, G13=f*M13+cy*M23;
        const float G20=M20,          G21=M21,          G22=M22,          G23=M23;
        Q[j][0]  = rfl(G00*rf);  Q[j][1]  = rfl(G01*rf);
        Q[j][2]  = rfl(G02 - (cx*rf)*G00 - (cy*rf)*G01);  Q[j][3]  = rfl(G03);
        Q[j][4]  = rfl(G10*rf);  Q[j][5]  = rfl(G11*rf);
        Q[j][6]  = rfl(G12 - (cx*rf)*G10 - (cy*rf)*G11);  Q[j][7]  = rfl(G13);
        Q[j][8]  = rfl(G20*rf);  Q[j][9]  = rfl(G21*rf);
        Q[j][10] = rfl(G22 - (cx*rf)*G20 - (cy*rf)*G21);  Q[j][11] = rfl(G23);
    }
}

// ---------- Stage 1: predicate + LDS block compaction -> per-(b,i) lists ----
// (R11's verified form: one global atomic per BLOCK; block-sequential burst write.)
__global__ __launch_bounds__(TPB) void compact_kernel(const float* __restrict__ pred,
                                                      const float* __restrict__ K,
                                                      const float* __restrict__ RT,
                                                      unsigned* __restrict__ list_cnt,
                                                      uint2* __restrict__ lists) {
    const int id   = blockIdx.x;
    const int b    = id & 7;
    const int r    = id >> 3;
    const int i    = r % Vn;
    const int xblk = r / Vn;
    const int L    = b * Vn + i;

    float Q[Vn][12];
    computeQ(K, RT, b, i, Q);

    __shared__ uint2 s_buf[TPB * PX];   // 16 KB
    __shared__ unsigned s_cnt, s_gbase;
    if (threadIdx.x == 0) s_cnt = 0u;
    __syncthreads();

    const int base = (xblk * TPB + threadIdx.x) * PX;
    const int yrow = base / Wn;
    const int xcol = base - yrow * Wn;
    const float fy = (float)yrow;

    const float* dptr = pred + (size_t)L * Nn + base;
    float dv[PX];
    {
        const float4 a0 = *reinterpret_cast<const float4*>(dptr);
        const float4 a1 = *reinterpret_cast<const float4*>(dptr + 4);
        dv[0] = a0.x; dv[1] = a0.y; dv[2] = a0.z; dv[3] = a0.w;
        dv[4] = a1.x; dv[5] = a1.y; dv[6] = a1.z; dv[7] = a1.w;
    }

    float RXc[Vn], RYc[Vn];
    #pragma unroll
    for (int j = 0; j < Vn; ++j) {
        RXc[j] = fmaf(Q[j][1], fy, Q[j][2]);
        RYc[j] = fmaf(Q[j][5], fy, Q[j][6]);
    }

    const int lane = threadIdx.x & 63;
    #pragma unroll
    for (int k = 0; k < PX; ++k) {
        const float d  = dv[k];
        const float fx = (float)(xcol + k);
        bool act = false;
        #pragma unroll
        for (int j = 0; j < Vn; ++j) {
            const float X = fmaf(d, fmaf(Q[j][0], fx, RXc[j]), Q[j][3]);
            const float Y = fmaf(d, fmaf(Q[j][4], fx, RYc[j]), Q[j][7]);
            act |= (X >= 0.0f) & (X <= (float)(Wn - 1)) &
                   (Y >= 0.0f) & (Y <= (float)(Hn - 1));
        }
        const unsigned long long m = __ballot(act);
        const int cnt = __popcll(m);
        unsigned wbase = 0;
        if (lane == 0 && cnt) wbase = atomicAdd(&s_cnt, (unsigned)cnt);
        wbase = (unsigned)__shfl((int)wbase, 0, 64);
        if (act) {
            const int pr = __popcll(m & ((1ULL << lane) - 1ULL));
            s_buf[wbase + pr] = make_uint2((unsigned)(xcol + k) | ((unsigned)yrow << 16),
                                           __float_as_uint(d));
        }
    }
    __syncthreads();
    if (threadIdx.x == 0) s_gbase = atomicAdd(&list_cnt[L], s_cnt);
    __syncthreads();
    const unsigned n = s_cnt, g = s_gbase;
    uint2* dst = lists + (size_t)L * CAPL;
    for (unsigned t = threadIdx.x; t < n; t += TPB) {
        const unsigned slot = g + t;
        if (slot < CAPL) dst[slot] = s_buf[t];
    }
}

// ---------- Stage 2: dense dual-record processing; fused finalize ----------
__global__ __launch_bounds__(TPB) void pairs_kernel(const float* __restrict__ pred,
                                                    const float* __restrict__ K,
                                                    const float* __restrict__ RT,
                                                    const unsigned* __restrict__ list_cnt,
                                                    const uint2* __restrict__ lists,
                                                    float* __restrict__ accum,
                                                    unsigned* __restrict__ counter,
                                                    float* __restrict__ out) {
    const int id    = blockIdx.x;
    const int b     = id & 7;          // XCD-batch locality (fully-resident grid!)
    const int r     = id >> 3;
    const int i     = r % Vn;
    const int chunk = r / Vn;
    const int L     = b * Vn + i;

    float Q[Vn][12];
    computeQ(K, RT, b, i, Q);

    unsigned count = list_cnt[L];
    if (count > CAPL) count = CAPL;
    const uint2* __restrict__ myl = lists + (size_t)L * CAPL;

    const float cW = (float)Wn / (float)(Wn - 1);
    const float cH = (float)Hn / (float)(Hn - 1);
    const unsigned step = NCH * TPB;

    float num[Vn] = {0.0f, 0.0f, 0.0f};
    float den[Vn] = {0.0f, 0.0f, 0.0f};

    for (unsigned t = (unsigned)chunk * TPB + threadIdx.x; t < count; t += 2u * step) {
        const unsigned t1 = t + step;
        const bool v1 = (t1 < count);
        const uint2 rec0 = myl[t];
        const uint2 rec1 = v1 ? myl[t1] : rec0;

        float fxq[2], fyq[2], dq[2];
        fxq[0] = (float)(rec0.x & 0xffffu); fyq[0] = (float)(rec0.x >> 16);
        dq[0]  = __uint_as_float(rec0.y);
        fxq[1] = (float)(rec1.x & 0xffffu); fyq[1] = (float)(rec1.x >> 16);
        dq[1]  = __uint_as_float(rec1.y);
        const bool vq[2] = {true, v1};

        int   ad0[2][Vn], ad1[2][Vn];
        float w00[2][Vn], w10[2][Vn], wy0v[2][Vn], wy1v[2][Vn], Zs[2][Vn], ms[2][Vn];
        bool  xloA[2][Vn], xhiA[2][Vn];
        #pragma unroll
        for (int q = 0; q < 2; ++q) {
            const float d = dq[q], fx = fxq[q], fyr = fyq[q];
            #pragma unroll
            for (int j = 0; j < Vn; ++j) {
                const float RXd = fmaf(Q[j][1], fyr, Q[j][2]);
                const float RYd = fmaf(Q[j][5], fyr, Q[j][6]);
                const float RZd = fmaf(Q[j][9], fyr, Q[j][10]);
                const float X = fmaf(d, fmaf(Q[j][0], fx, RXd), Q[j][3]);
                const float Y = fmaf(d, fmaf(Q[j][4], fx, RYd), Q[j][7]);
                const float Z = fmaf(d, fmaf(Q[j][8], fx, RZd), Q[j][11]);
                const bool inb = vq[q] & (X >= 0.0f) & (X <= (float)(Wn - 1)) &
                                         (Y >= 0.0f) & (Y <= (float)(Hn - 1));
                const float ix = fmaf(X, cW, -0.5f);
                const float iy = fmaf(Y, cH, -0.5f);
                const float x0f = floorf(ix);
                const float y0f = floorf(iy);
                const float wx1 = ix - x0f;
                const float wy1 = iy - y0f;
                const float wx0 = 1.0f - wx1;
                const float wy0 = 1.0f - wy1;
                const int x0 = (int)x0f;
                const int y0 = (int)y0f;
                const int x1 = x0 + 1;
                const int y1 = y0 + 1;
                const int cx2 = min(max(x0, 0), Wn - 2);
                const int cy0 = min(max(y0, 0), Hn - 1);
                const int cy1 = min(max(y1, 0), Hn - 1);
                ad0[q][j] = cy0 * Wn + cx2;
                ad1[q][j] = cy1 * Wn + cx2;
                xloA[q][j] = (x0 >= 0);
                xhiA[q][j] = (x0 <= Wn - 2);
                w00[q][j]  = (inb && xloA[q][j])   ? wx0 : 0.0f;
                w10[q][j]  = (inb && (x1 < Wn))    ? wx1 : 0.0f;
                wy0v[q][j] = (inb && (y0 >= 0))    ? wy0 : 0.0f;
                wy1v[q][j] = (inb && (y1 < Hn))    ? wy1 : 0.0f;
                Zs[q][j]   = inb ? Z : 0.0f;
                ms[q][j]   = inb ? 1.0f : 0.0f;
            }
        }
        fpair q0[2][Vn], q1[2][Vn];
        #pragma unroll
        for (int q = 0; q < 2; ++q)
            #pragma unroll
            for (int j = 0; j < Vn; ++j) {
                const float* img = pred + (size_t)(b * Vn + j) * Nn;
                q0[q][j] = *reinterpret_cast<const fpair*>(img + ad0[q][j]);
                q1[q][j] = *reinterpret_cast<const fpair*>(img + ad1[q][j]);
            }
        #pragma unroll
        for (int q = 0; q < 2; ++q)
            #pragma unroll
            for (int j = 0; j < Vn; ++j) {
                const float c00 = xhiA[q][j] ? q0[q][j].a : q0[q][j].b;
                const float c10 = xloA[q][j] ? q0[q][j].b : q0[q][j].a;
                const float c01 = xhiA[q][j] ? q1[q][j].a : q1[q][j].b;
                const float c11 = xloA[q][j] ? q1[q][j].b : q1[q][j].a;
                const float top = fmaf(w00[q][j], c00, w10[q][j] * c10);
                const float bot = fmaf(w00[q][j], c01, w10[q][j] * c11);
                const float warped = fmaf(wy0v[q][j], top, wy1v[q][j] * bot);
                num[j] += fabsf(warped - Zs[q][j]);
                den[j] += ms[q][j];
            }
    }

    // reduction: wave-64 shuffle over 6 accumulators
    #pragma unroll
    for (int off = 32; off > 0; off >>= 1) {
        #pragma unroll
        for (int j = 0; j < Vn; ++j) {
            num[j] += __shfl_down(num[j], off, 64);
            den[j] += __shfl_down(den[j], off, 64);
        }
    }
    __shared__ float s_red[4][2 * Vn];
    __shared__ int s_last;
    const int lane = threadIdx.x & 63;
    const int wid  = threadIdx.x >> 6;
    if (lane == 0) {
        #pragma unroll
        for (int j = 0; j < Vn; ++j) {
            s_red[wid][2 * j + 0] = num[j];
            s_red[wid][2 * j + 1] = den[j];
        }
    }
    __syncthreads();
    if (threadIdx.x < 2 * Vn) {
        const int slot = threadIdx.x;
        const float v = s_red[0][slot] + s_red[1][slot] + s_red[2][slot] + s_red[3][slot];
        const int j = slot >> 1;
        const int comp = slot & 1;
        atomicAdd(&accum[(i * Vn + j) * 2 + comp], v);
    }
    __syncthreads();
    if (threadIdx.x == 0) {
        __threadfence();
        const unsigned old = atomicAdd(counter, 1u);
        s_last = (old == (unsigned)(GRID2 - 1)) ? 1 : 0;
    }
    __syncthreads();
    if (s_last && threadIdx.x == 0) {
        float tt = 0.0f;
        for (int pr = 0; pr < Vn * Vn; ++pr) {
            const float nn = atomicAdd(&accum[pr * 2 + 0], 0.0f);
            const float dd = atomicAdd(&accum[pr * 2 + 1], 0.0f);
            tt += nn / fmaxf(dd, 1.0f);
        }
        out[0] = tt;
    }
}

extern "C" void kernel_launch(void* const* d_in, const int* in_sizes, int n_in,
                              void* d_out, int out_size, void* d_ws, size_t ws_size,
                              hipStream_t stream) {
    const float* pred = (const float*)d_in[0];   // (B,V,H,W)
    const float* K    = (const float*)d_in[1];   // (B,4,4)
    const float* RT   = (const float*)d_in[2];   // (B,V,4,4)
    float* out = (float*)d_out;

    float*    accum    = (float*)d_ws;                    // 24 floats
    unsigned* counter  = (unsigned*)d_ws + 24;            // ticket
    unsigned* list_cnt = (unsigned*)d_ws + 32;            // 24 counters
    uint2*    lists    = (uint2*)((char*)d_ws + 1024);    // 24*CAPL*8B = 25 MB

    hipMemsetAsync(d_ws, 0, 512, stream);
    compact_kernel<<<GRID1, TPB, 0, stream>>>(pred, K, RT, list_cnt, lists);
    pairs_kernel<<<GRID2, TPB, 0, stream>>>(pred, K, RT, list_cnt, lists,
                                            accum, counter, out);
}

// Round 14
// 140.531 us; speedup vs baseline: 2.2345x; 1.2785x over previous
//
#include <hip/hip_runtime.h>

#define Bn 8
#define Vn 3
#define Hn 512
#define Wn 640
#define Nn (Hn * Wn)
#define PX 8                      // pixels per thread in compact
#define TPB 256
#define XBLKS (Nn / (TPB * PX))   // 160 blocks per (b,i)
#define GRID1 (XBLKS * Vn * Bn)   // 3840
#define CAPL 131072               // records per (b,i) list (expect ~85-100k)
#define NCH 32                    // chunks per list -> GRID2 = 768 (R11 champion)
#define GRID2 (Bn * Vn * NCH)

struct __attribute__((aligned(4))) fpair { float a, b; };

__device__ __forceinline__ float rfl(float x) {
    return __int_as_float(__builtin_amdgcn_readfirstlane(__float_as_int(x)));
}

// Inline P = K * RT_j * inv(RT_i) * inv(K), rows 0..2, analytic affine inverses.
// Identical in both kernels -> compact's predicate == pairs' inb bitwise.
// (Validated R10/R11: absmax 0.0 vs reference.)
__device__ __forceinline__ void computeQ(const float* __restrict__ K,
                                         const float* __restrict__ RT,
                                         int b, int i, float Q[Vn][12]) {
    const float* Kb = K + (size_t)b * 16;
    const float f  = Kb[0], cx = Kb[2], cy = Kb[6];
    const float rf = 1.0f / f;
    const float* Ti = RT + (size_t)(b * Vn + i) * 16;
    const float A00=Ti[0], A01=Ti[1], A02=Ti[2],  A03=Ti[3];
    const float A10=Ti[4], A11=Ti[5], A12=Ti[6],  A13=Ti[7];
    const float A20=Ti[8], A21=Ti[9], A22=Ti[10], A23=Ti[11];
    const float I00=A00, I01=A10, I02=A20, I03=-(A00*A03 + A10*A13 + A20*A23);
    const float I10=A01, I11=A11, I12=A21, I13=-(A01*A03 + A11*A13 + A21*A23);
    const float I20=A02, I21=A12, I22=A22, I23=-(A02*A03 + A12*A13 + A22*A23);
    #pragma unroll
    for (int j = 0; j < Vn; ++j) {
        const float* Tj = RT + (size_t)(b * Vn + j) * 16;
        const float B00=Tj[0], B01=Tj[1], B02=Tj[2],  B03=Tj[3];
        const float B10=Tj[4], B11=Tj[5], B12=Tj[6],  B13=Tj[7];
        const float B20=Tj[8], B21=Tj[9], B22=Tj[10], B23=Tj[11];
        const float M00=B00*I00+B01*I10+B02*I20, M01=B00*I01+B01*I11+B02*I21,
                    M02=B00*I02+B01*I12+B02*I22, M03=B00*I03+B01*I13+B02*I23+B03;
        const float M10=B10*I00+B11*I10+B12*I20, M11=B10*I01+B11*I11+B12*I21,
                    M12=B10*I02+B11*I12+B12*I22, M13=B10*I03+B11*I13+B12*I23+B13;
        const float M20=B20*I00+B21*I10+B22*I20, M21=B20*I01+B21*I11+B22*I21,
                    M22=B20*I02+B21*I12+B22*I22, M23=B20*I03+B21*I13+B22*I23+B23;
        const float G00=f*M00+cx*M20, G01=f*M01+cx*M21, G02=f*M02+cx*M22, G03=f*M03+cx*M23;
        const float G10=f*M10+cy*M20, G11=f*M11+cy*M21, G12=f*M12+cy*M22, G13=f*M13+cy*M23;
        const float G20=M20,          G21=M21,          G22=M22,          G23=M23;
        Q[j][0]  = rfl(G00*rf);  Q[j][1]  = rfl(G01*rf);
        Q[j][2]  = rfl(G02 - (cx*rf)*G00 - (cy*rf)*G01);  Q[j][3]  = rfl(G03);
        Q[j][4]  = rfl(G10*rf);  Q[j][5]  = rfl(G11*rf);
        Q[j][6]  = rfl(G12 - (cx*rf)*G10 - (cy*rf)*G11);  Q[j][7]  = rfl(G13);
        Q[j][8]  = rfl(G20*rf);  Q[j][9]  = rfl(G21*rf);
        Q[j][10] = rfl(G22 - (cx*rf)*G20 - (cy*rf)*G21);  Q[j][11] = rfl(G23);
    }
}

// ---------- Stage 1: predicate + LDS block compaction -> per-(b,i) lists ----
__global__ __launch_bounds__(TPB) void compact_kernel(const float* __restrict__ pred,
                                                      const float* __restrict__ K,
                                                      const float* __restrict__ RT,
                                                      unsigned* __restrict__ list_cnt,
                                                      uint2* __restrict__ lists) {
    const int id   = blockIdx.x;
    const int b    = id & 7;
    const int r    = id >> 3;
    const int i    = r % Vn;
    const int xblk = r / Vn;
    const int L    = b * Vn + i;

    float Q[Vn][12];
    computeQ(K, RT, b, i, Q);

    __shared__ uint2 s_buf[TPB * PX];   // 16 KB
    __shared__ unsigned s_cnt, s_gbase;
    if (threadIdx.x == 0) s_cnt = 0u;
    __syncthreads();

    const int base = (xblk * TPB + threadIdx.x) * PX;
    const int yrow = base / Wn;
    const int xcol = base - yrow * Wn;
    const float fy = (float)yrow;

    const float* dptr = pred + (size_t)L * Nn + base;
    float dv[PX];
    {
        const float4 a0 = *reinterpret_cast<const float4*>(dptr);
        const float4 a1 = *reinterpret_cast<const float4*>(dptr + 4);
        dv[0] = a0.x; dv[1] = a0.y; dv[2] = a0.z; dv[3] = a0.w;
        dv[4] = a1.x; dv[5] = a1.y; dv[6] = a1.z; dv[7] = a1.w;
    }

    float RXc[Vn], RYc[Vn];
    #pragma unroll
    for (int j = 0; j < Vn; ++j) {
        RXc[j] = fmaf(Q[j][1], fy, Q[j][2]);
        RYc[j] = fmaf(Q[j][5], fy, Q[j][6]);
    }

    const int lane = threadIdx.x & 63;
    #pragma unroll
    for (int k = 0; k < PX; ++k) {
        const float d  = dv[k];
        const float fx = (float)(xcol + k);
        bool act = false;
        #pragma unroll
        for (int j = 0; j < Vn; ++j) {
            const float X = fmaf(d, fmaf(Q[j][0], fx, RXc[j]), Q[j][3]);
            const float Y = fmaf(d, fmaf(Q[j][4], fx, RYc[j]), Q[j][7]);
            act |= (X >= 0.0f) & (X <= (float)(Wn - 1)) &
                   (Y >= 0.0f) & (Y <= (float)(Hn - 1));
        }
        const unsigned long long m = __ballot(act);
        const int cnt = __popcll(m);
        unsigned wbase = 0;
        if (lane == 0 && cnt) wbase = atomicAdd(&s_cnt, (unsigned)cnt);
        wbase = (unsigned)__shfl((int)wbase, 0, 64);
        if (act) {
            const int pr = __popcll(m & ((1ULL << lane) - 1ULL));
            s_buf[wbase + pr] = make_uint2((unsigned)(xcol + k) | ((unsigned)yrow << 16),
                                           __float_as_uint(d));
        }
    }
    __syncthreads();
    if (threadIdx.x == 0) s_gbase = atomicAdd(&list_cnt[L], s_cnt);
    __syncthreads();
    const unsigned n = s_cnt, g = s_gbase;
    uint2* dst = lists + (size_t)L * CAPL;
    for (unsigned t = threadIdx.x; t < n; t += TPB) {
        const unsigned slot = g + t;
        if (slot < CAPL) dst[slot] = s_buf[t];
    }
}

// ---------- Stage 2: dense dual-record processing (NO fence, NO ticket) ----------
__global__ __launch_bounds__(TPB) void pairs_kernel(const float* __restrict__ pred,
                                                    const float* __restrict__ K,
                                                    const float* __restrict__ RT,
                                                    const unsigned* __restrict__ list_cnt,
                                                    const uint2* __restrict__ lists,
                                                    float* __restrict__ accum) {
    const int id    = blockIdx.x;
    const int b     = id & 7;          // XCD-batch locality (fully-resident grid)
    const int r     = id >> 3;
    const int i     = r % Vn;
    const int chunk = r / Vn;
    const int L     = b * Vn + i;

    float Q[Vn][12];
    computeQ(K, RT, b, i, Q);

    unsigned count = list_cnt[L];
    if (count > CAPL) count = CAPL;
    const uint2* __restrict__ myl = lists + (size_t)L * CAPL;

    const float cW = (float)Wn / (float)(Wn - 1);
    const float cH = (float)Hn / (float)(Hn - 1);
    const unsigned step = NCH * TPB;

    float num[Vn] = {0.0f, 0.0f, 0.0f};
    float den[Vn] = {0.0f, 0.0f, 0.0f};

    for (unsigned t = (unsigned)chunk * TPB + threadIdx.x; t < count; t += 2u * step) {
        const unsigned t1 = t + step;
        const bool v1 = (t1 < count);
        const uint2 rec0 = myl[t];
        const uint2 rec1 = v1 ? myl[t1] : rec0;

        float fxq[2], fyq[2], dq[2];
        fxq[0] = (float)(rec0.x & 0xffffu); fyq[0] = (float)(rec0.x >> 16);
        dq[0]  = __uint_as_float(rec0.y);
        fxq[1] = (float)(rec1.x & 0xffffu); fyq[1] = (float)(rec1.x >> 16);
        dq[1]  = __uint_as_float(rec1.y);
        const bool vq[2] = {true, v1};

        int   ad0[2][Vn], ad1[2][Vn];
        float w00[2][Vn], w10[2][Vn], wy0v[2][Vn], wy1v[2][Vn], Zs[2][Vn], ms[2][Vn];
        bool  xloA[2][Vn], xhiA[2][Vn];
        #pragma unroll
        for (int q = 0; q < 2; ++q) {
            const float d = dq[q], fx = fxq[q], fyr = fyq[q];
            #pragma unroll
            for (int j = 0; j < Vn; ++j) {
                const float RXd = fmaf(Q[j][1], fyr, Q[j][2]);
                const float RYd = fmaf(Q[j][5], fyr, Q[j][6]);
                const float RZd = fmaf(Q[j][9], fyr, Q[j][10]);
                const float X = fmaf(d, fmaf(Q[j][0], fx, RXd), Q[j][3]);
                const float Y = fmaf(d, fmaf(Q[j][4], fx, RYd), Q[j][7]);
                const float Z = fmaf(d, fmaf(Q[j][8], fx, RZd), Q[j][11]);
                const bool inb = vq[q] & (X >= 0.0f) & (X <= (float)(Wn - 1)) &
                                         (Y >= 0.0f) & (Y <= (float)(Hn - 1));
                const float ix = fmaf(X, cW, -0.5f);
                const float iy = fmaf(Y, cH, -0.5f);
                const float x0f = floorf(ix);
                const float y0f = floorf(iy);
                const float wx1 = ix - x0f;
                const float wy1 = iy - y0f;
                const float wx0 = 1.0f - wx1;
                const float wy0 = 1.0f - wy1;
                const int x0 = (int)x0f;
                const int y0 = (int)y0f;
                const int x1 = x0 + 1;
                const int y1 = y0 + 1;
                const int cx2 = min(max(x0, 0), Wn - 2);
                const int cy0 = min(max(y0, 0), Hn - 1);
                const int cy1 = min(max(y1, 0), Hn - 1);
                ad0[q][j] = cy0 * Wn + cx2;
                ad1[q][j] = cy1 * Wn + cx2;
                xloA[q][j] = (x0 >= 0);
                xhiA[q][j] = (x0 <= Wn - 2);
                w00[q][j]  = (inb && xloA[q][j])   ? wx0 : 0.0f;
                w10[q][j]  = (inb && (x1 < Wn))    ? wx1 : 0.0f;
                wy0v[q][j] = (inb && (y0 >= 0))    ? wy0 : 0.0f;
                wy1v[q][j] = (inb && (y1 < Hn))    ? wy1 : 0.0f;
                Zs[q][j]   = inb ? Z : 0.0f;
                ms[q][j]   = inb ? 1.0f : 0.0f;
            }
        }
        fpair q0[2][Vn], q1[2][Vn];
        #pragma unroll
        for (int q = 0; q < 2; ++q)
            #pragma unroll
            for (int j = 0; j < Vn; ++j) {
                const float* img = pred + (size_t)(b * Vn + j) * Nn;
                q0[q][j] = *reinterpret_cast<const fpair*>(img + ad0[q][j]);
                q1[q][j] = *reinterpret_cast<const fpair*>(img + ad1[q][j]);
            }
        #pragma unroll
        for (int q = 0; q < 2; ++q)
            #pragma unroll
            for (int j = 0; j < Vn; ++j) {
                const float c00 = xhiA[q][j] ? q0[q][j].a : q0[q][j].b;
                const float c10 = xloA[q][j] ? q0[q][j].b : q0[q][j].a;
                const float c01 = xhiA[q][j] ? q1[q][j].a : q1[q][j].b;
                const float c11 = xloA[q][j] ? q1[q][j].b : q1[q][j].a;
                const float top = fmaf(w00[q][j], c00, w10[q][j] * c10);
                const float bot = fmaf(w00[q][j], c01, w10[q][j] * c11);
                const float warped = fmaf(wy0v[q][j], top, wy1v[q][j] * bot);
                num[j] += fabsf(warped - Zs[q][j]);
                den[j] += ms[q][j];
            }
    }

    // reduction: wave-64 shuffle over 6 accumulators
    #pragma unroll
    for (int off = 32; off > 0; off >>= 1) {
        #pragma unroll
        for (int j = 0; j < Vn; ++j) {
            num[j] += __shfl_down(num[j], off, 64);
            den[j] += __shfl_down(den[j], off, 64);
        }
    }
    __shared__ float s_red[4][2 * Vn];
    const int lane = threadIdx.x & 63;
    const int wid  = threadIdx.x >> 6;
    if (lane == 0) {
        #pragma unroll
        for (int j = 0; j < Vn; ++j) {
            s_red[wid][2 * j + 0] = num[j];
            s_red[wid][2 * j + 1] = den[j];
        }
    }
    __syncthreads();
    if (threadIdx.x < 2 * Vn) {
        const int slot = threadIdx.x;
        const float v = s_red[0][slot] + s_red[1][slot] + s_red[2][slot] + s_red[3][slot];
        const int j = slot >> 1;
        const int comp = slot & 1;
        atomicAdd(&accum[(i * Vn + j) * 2 + comp], v);   // device-scope atomic
    }
    // no fence, no ticket: finalize is a separate dispatch (kernel-boundary coherence)
}

// ---------- Stage 3: total = sum_ij num/max(den,1) ----------
__global__ void finalize_kernel(const float* __restrict__ accum, float* __restrict__ out) {
    if (threadIdx.x == 0 && blockIdx.x == 0) {
        float t = 0.0f;
        for (int pr = 0; pr < Vn * Vn; ++pr) {
            t += accum[pr * 2 + 0] / fmaxf(accum[pr * 2 + 1], 1.0f);
        }
        out[0] = t;
    }
}

extern "C" void kernel_launch(void* const* d_in, const int* in_sizes, int n_in,
                              void* d_out, int out_size, void* d_ws, size_t ws_size,
                              hipStream_t stream) {
    const float* pred = (const float*)d_in[0];   // (B,V,H,W)
    const float* K    = (const float*)d_in[1];   // (B,4,4)
    const float* RT   = (const float*)d_in[2];   // (B,V,4,4)
    float* out = (float*)d_out;

    float*    accum    = (float*)d_ws;                    // 24 floats
    unsigned* list_cnt = (unsigned*)d_ws + 32;            // 24 counters
    uint2*    lists    = (uint2*)((char*)d_ws + 1024);    // 24*CAPL*8B = 25 MB

    hipMemsetAsync(d_ws, 0, 512, stream);
    compact_kernel<<<GRID1, TPB, 0, stream>>>(pred, K, RT, list_cnt, lists);
    pairs_kernel<<<GRID2, TPB, 0, stream>>>(pred, K, RT, list_cnt, lists, accum);
    finalize_kernel<<<1, 64, 0, stream>>>(accum, out);
}

// Round 15
// 136.839 us; speedup vs baseline: 2.2947x; 1.0270x over previous
//
#include <hip/hip_runtime.h>

#define Bn 8
#define Vn 3
#define Hn 512
#define Wn 640
#define Nn (Hn * Wn)
#define PX 8                      // pixels per thread (8 divides 640: no row wrap)
#define TPB 256
#define XBLKS (Nn / (TPB * PX))   // 160
#define GRIDN (XBLKS * Vn * Bn)   // 3840 blocks

struct __attribute__((aligned(4))) fpair { float a, b; };

__device__ __forceinline__ float rfl(float x) {
    return __int_as_float(__builtin_amdgcn_readfirstlane(__float_as_int(x)));
}

// Inline P = K * RT_j * inv(RT_i) * inv(K), rows 0..2, analytic affine inverses
// (inv([R|t]) = [R^T | -R^T t]; Kinv analytic). Bottom row of P is exactly
// [0,0,0,1] -> reference's divide-by-proj[3] is a no-op; skip row 3.
// Validated R10/R11/R14: absmax 0.0 vs reference's numerical inverses.
__device__ __forceinline__ void computeQ(const float* __restrict__ K,
                                         const float* __restrict__ RT,
                                         int b, int i, float Q[Vn][12]) {
    const float* Kb = K + (size_t)b * 16;
    const float f  = Kb[0], cx = Kb[2], cy = Kb[6];
    const float rf = 1.0f / f;
    const float* Ti = RT + (size_t)(b * Vn + i) * 16;
    const float A00=Ti[0], A01=Ti[1], A02=Ti[2],  A03=Ti[3];
    const float A10=Ti[4], A11=Ti[5], A12=Ti[6],  A13=Ti[7];
    const float A20=Ti[8], A21=Ti[9], A22=Ti[10], A23=Ti[11];
    const float I00=A00, I01=A10, I02=A20, I03=-(A00*A03 + A10*A13 + A20*A23);
    const float I10=A01, I11=A11, I12=A21, I13=-(A01*A03 + A11*A13 + A21*A23);
    const float I20=A02, I21=A12, I22=A22, I23=-(A02*A03 + A12*A13 + A22*A23);
    #pragma unroll
    for (int j = 0; j < Vn; ++j) {
        const float* Tj = RT + (size_t)(b * Vn + j) * 16;
        const float B00=Tj[0], B01=Tj[1], B02=Tj[2],  B03=Tj[3];
        const float B10=Tj[4], B11=Tj[5], B12=Tj[6],  B13=Tj[7];
        const float B20=Tj[8], B21=Tj[9], B22=Tj[10], B23=Tj[11];
        const float M00=B00*I00+B01*I10+B02*I20, M01=B00*I01+B01*I11+B02*I21,
                    M02=B00*I02+B01*I12+B02*I22, M03=B00*I03+B01*I13+B02*I23+B03;
        const float M10=B10*I00+B11*I10+B12*I20, M11=B10*I01+B11*I11+B12*I21,
                    M12=B10*I02+B11*I12+B12*I22, M13=B10*I03+B11*I13+B12*I23+B13;
        const float M20=B20*I00+B21*I10+B22*I20, M21=B20*I01+B21*I11+B22*I21,
                    M22=B20*I02+B21*I12+B22*I22, M23=B20*I03+B21*I13+B22*I23+B23;
        const float G00=f*M00+cx*M20, G01=f*M01+cx*M21, G02=f*M02+cx*M22, G03=f*M03+cx*M23;
        const float G10=f*M10+cy*M20, G11=f*M11+cy*M21, G12=f*M12+cy*M22, G13=f*M13+cy*M23;
        const float G20=M20,          G21=M21,          G22=M22,          G23=M23;
        Q[j][0]  = rfl(G00*rf);  Q[j][1]  = rfl(G01*rf);
        Q[j][2]  = rfl(G02 - (cx*rf)*G00 - (cy*rf)*G01);  Q[j][3]  = rfl(G03);
        Q[j][4]  = rfl(G10*rf);  Q[j][5]  = rfl(G11*rf);
        Q[j][6]  = rfl(G12 - (cx*rf)*G10 - (cy*rf)*G11);  Q[j][7]  = rfl(G13);
        Q[j][8]  = rfl(G20*rf);  Q[j][9]  = rfl(G21*rf);
        Q[j][10] = rfl(G22 - (cx*rf)*G20 - (cy*rf)*G21);  Q[j][11] = rfl(G23);
    }
}

// ---------- Main: R7's exec-masked gather body; NO fence, NO ticket ----------
__global__ __launch_bounds__(TPB) void loss_main_kernel(const float* __restrict__ pred,
                                                        const float* __restrict__ K,
                                                        const float* __restrict__ RT,
                                                        float* __restrict__ accum) {
    // b = blockIdx.x % 8: XCD-batch L2 locality (one batch's 3 planes = 3.93 MB).
    const int id   = blockIdx.x;
    const int b    = id & 7;
    const int r    = id >> 3;
    const int i    = r % Vn;
    const int xblk = r / Vn;

    float Q[Vn][12];
    computeQ(K, RT, b, i, Q);

    const int base = (xblk * TPB + threadIdx.x) * PX;
    const int yrow = base / Wn;
    const int xcol = base - yrow * Wn;
    const float fy = (float)yrow;

    const float* dptr = pred + (size_t)(b * Vn + i) * Nn + base;
    float dv[PX];
    {
        const float4 a0 = *reinterpret_cast<const float4*>(dptr);
        const float4 a1 = *reinterpret_cast<const float4*>(dptr + 4);
        dv[0] = a0.x; dv[1] = a0.y; dv[2] = a0.z; dv[3] = a0.w;
        dv[4] = a1.x; dv[5] = a1.y; dv[6] = a1.z; dv[7] = a1.w;
    }

    const float cW = (float)Wn / (float)(Wn - 1);   // ix = X*cW - 0.5
    const float cH = (float)Hn / (float)(Hn - 1);

    float num[Vn] = {0.0f, 0.0f, 0.0f};
    float den[Vn] = {0.0f, 0.0f, 0.0f};

    #pragma unroll
    for (int j = 0; j < Vn; ++j) {
        const float* __restrict__ img = pred + (size_t)(b * Vn + j) * Nn;
        // per-row (fy) constants for this thread
        const float rx = fmaf(Q[j][1], fy, Q[j][2]);
        const float ry = fmaf(Q[j][5], fy, Q[j][6]);
        const float rz = fmaf(Q[j][9], fy, Q[j][10]);

        #pragma unroll
        for (int k = 0; k < PX; ++k) {
            const float d  = dv[k];
            const float fx = (float)(xcol + k);

            const float X = fmaf(d, fmaf(Q[j][0], fx, rx), Q[j][3]);
            const float Y = fmaf(d, fmaf(Q[j][4], fx, ry), Q[j][7]);
            const float Z = fmaf(d, fmaf(Q[j][8], fx, rz), Q[j][11]);

            const bool inb = (X >= 0.0f) & (X <= (float)(Wn - 1)) &
                             (Y >= 0.0f) & (Y <= (float)(Hn - 1));
            if (inb) {
                const float ix = fmaf(X, cW, -0.5f);
                const float iy = fmaf(Y, cH, -0.5f);
                const float x0f = floorf(ix);
                const float y0f = floorf(iy);
                const float wx1 = ix - x0f;
                const float wy1 = iy - y0f;
                const float wx0 = 1.0f - wx1;
                const float wy0 = 1.0f - wy1;
                const int x0 = (int)x0f;           // in [-1, W-1]
                const int y0 = (int)y0f;           // in [-1, H-1]
                const int x1 = x0 + 1;
                const int y1 = y0 + 1;
                const int cy0 = max(y0, 0);
                const int cy1 = min(y1, Hn - 1);

                // paired-corner load: both x-neighbors in ONE 8B load per row
                const int cx   = min(max(x0, 0), Wn - 2);
                const bool xlo = (x0 >= 0);
                const bool xhi = (x0 <= Wn - 2);
                const fpair q0 = *reinterpret_cast<const fpair*>(img + (cy0 * Wn + cx));
                const fpair q1 = *reinterpret_cast<const fpair*>(img + (cy1 * Wn + cx));
                const float c00 = xhi ? q0.a : q0.b;
                const float c10 = xlo ? q0.b : q0.a;
                const float c01 = xhi ? q1.a : q1.b;
                const float c11 = xlo ? q1.b : q1.a;

                const float wx0v = xlo ? wx0 : 0.0f;
                const float wx1v = (x1 < Wn) ? wx1 : 0.0f;
                const float wy0v = (y0 >= 0) ? wy0 : 0.0f;
                const float wy1v = (y1 < Hn) ? wy1 : 0.0f;

                const float warped = wy0v * fmaf(wx0v, c00, wx1v * c10)
                                   + wy1v * fmaf(wx0v, c01, wx1v * c11);
                num[j] += fabsf(warped - Z);
                den[j] += 1.0f;
            }
        }
    }

    // wave-64 shuffle reduction over 6 independent accumulators
    #pragma unroll
    for (int off = 32; off > 0; off >>= 1) {
        #pragma unroll
        for (int j = 0; j < Vn; ++j) {
            num[j] += __shfl_down(num[j], off, 64);
            den[j] += __shfl_down(den[j], off, 64);
        }
    }
    __shared__ float s_red[4][2 * Vn];
    const int lane = threadIdx.x & 63;
    const int wid  = threadIdx.x >> 6;
    if (lane == 0) {
        #pragma unroll
        for (int j = 0; j < Vn; ++j) {
            s_red[wid][2 * j + 0] = num[j];
            s_red[wid][2 * j + 1] = den[j];
        }
    }
    __syncthreads();
    if (threadIdx.x < 2 * Vn) {
        const int slot = threadIdx.x;
        const float v = s_red[0][slot] + s_red[1][slot] + s_red[2][slot] + s_red[3][slot];
        const int j = slot >> 1;
        const int comp = slot & 1;
        atomicAdd(&accum[(i * Vn + j) * 2 + comp], v);   // device-scope atomic
    }
    // no fence, no ticket: finalize is a separate dispatch (kernel-boundary coherence)
}

// ---------- Finalize: total = sum_ij num/max(den,1) ----------
__global__ void finalize_kernel(const float* __restrict__ accum, float* __restrict__ out) {
    if (threadIdx.x == 0 && blockIdx.x == 0) {
        float t = 0.0f;
        for (int pr = 0; pr < Vn * Vn; ++pr) {
            t += accum[pr * 2 + 0] / fmaxf(accum[pr * 2 + 1], 1.0f);
        }
        out[0] = t;
    }
}

extern "C" void kernel_launch(void* const* d_in, const int* in_sizes, int n_in,
                              void* d_out, int out_size, void* d_ws, size_t ws_size,
                              hipStream_t stream) {
    const float* pred = (const float*)d_in[0];   // (B,V,H,W)
    const float* K    = (const float*)d_in[1];   // (B,4,4)
    const float* RT   = (const float*)d_in[2];   // (B,V,4,4)
    float* out = (float*)d_out;

    float* accum = (float*)d_ws;                 // 18 floats used (num,den per pair)

    hipMemsetAsync(d_ws, 0, 128, stream);
    loss_main_kernel<<<GRIDN, TPB, 0, stream>>>(pred, K, RT, accum);
    finalize_kernel<<<1, 64, 0, stream>>>(accum, out);
}